// Round 9
// baseline (130.837 us; speedup 1.0000x reference)
//
#include <hip/hip_runtime.h>
#include <stdint.h>

typedef short bf16x8 __attribute__((ext_vector_type(8)));
typedef float f32x4  __attribute__((ext_vector_type(4)));
typedef float f32x2  __attribute__((ext_vector_type(2)));

__device__ __forceinline__ unsigned short f2bf(float f) {
    unsigned int u = __float_as_uint(f);
    u += 0x7FFFu + ((u >> 16) & 1u);
    return (unsigned short)(u >> 16);
}
__device__ __forceinline__ float bf2f(unsigned short h) {
    return __uint_as_float(((unsigned int)h) << 16);
}

// ---- kernel A: fold W1f = w1@wf, W2f = w2@wf (store transposed bf16), cb = b@wf ----
__global__ void fuse_weights(const float* __restrict__ w1, const float* __restrict__ b1,
                             const float* __restrict__ w2, const float* __restrict__ b2,
                             const float* __restrict__ wf,
                             unsigned short* __restrict__ wcT,  // [2][128 cols][128 k]
                             float* __restrict__ cb)            // [2][128]
{
    int mat = blockIdx.x / 129;
    int kk  = blockIdx.x % 129;
    int c   = threadIdx.x;
    const float* w = (mat == 0) ? w1 : w2;
    const float* b = (mat == 0) ? b1 : b2;
    float acc = 0.f;
    if (kk < 128) {
        #pragma unroll 8
        for (int j = 0; j < 128; ++j) acc += w[kk * 128 + j] * wf[j * 128 + c];
        wcT[mat * 16384 + c * 128 + kk] = f2bf(acc);
    } else {
        #pragma unroll 8
        for (int j = 0; j < 128; ++j) acc += b[j] * wf[j * 128 + c];
        cb[mat * 128 + c] = acc;
    }
}

// ---- kernel B: g[mat] = x @ Wc[mat] + cb[mat] -> bf16 [2][nrows][128] ----
// WAVE_ROWS=32: ~3128 waves (12/CU) to hide the cold x-load latency.
#define WAVE_ROWS 32
__global__ __launch_bounds__(256) void gemm_g(
    const float* __restrict__ x, const unsigned short* __restrict__ wcT,
    const float* __restrict__ cb, unsigned short* __restrict__ g, int nrows)
{
    int lane = threadIdx.x & 63;
    int wid  = threadIdx.x >> 6;
    int r0   = (blockIdx.x * 4 + wid) * WAVE_ROWS;
    if (r0 >= nrows) return;
    int lrow = lane & 15;
    int kg   = lane >> 4;

    bf16x8 xf[2][4];   // [rowtile][kstep]
    #pragma unroll
    for (int t = 0; t < 2; ++t) {
        int row = r0 + t * 16 + lrow;
        bool v  = row < nrows;
        #pragma unroll
        for (int ks = 0; ks < 4; ++ks) {
            int k0 = ks * 32 + kg * 8;
            f32x4 p0 = v ? __builtin_nontemporal_load((const f32x4*)(x + (size_t)row * 128 + k0))
                         : f32x4{0,0,0,0};
            f32x4 p1 = v ? __builtin_nontemporal_load((const f32x4*)(x + (size_t)row * 128 + k0 + 4))
                         : f32x4{0,0,0,0};
            bf16x8 f;
            f[0] = (short)f2bf(p0[0]); f[1] = (short)f2bf(p0[1]);
            f[2] = (short)f2bf(p0[2]); f[3] = (short)f2bf(p0[3]);
            f[4] = (short)f2bf(p1[0]); f[5] = (short)f2bf(p1[1]);
            f[6] = (short)f2bf(p1[2]); f[7] = (short)f2bf(p1[3]);
            xf[t][ks] = f;
        }
    }

    #pragma unroll
    for (int mat = 0; mat < 2; ++mat) {
        unsigned short* gm = g + (size_t)mat * nrows * 128;
        const unsigned short* wT = wcT + mat * 16384;
        #pragma unroll 2
        for (int c = 0; c < 8; ++c) {
            bf16x8 wfr[4];
            const unsigned short* wb = wT + (size_t)(c * 16 + lrow) * 128 + kg * 8;
            #pragma unroll
            for (int ks = 0; ks < 4; ++ks)
                wfr[ks] = *(const bf16x8*)(wb + ks * 32);
            f32x4 acc[2];
            #pragma unroll
            for (int t = 0; t < 2; ++t) acc[t] = f32x4{0,0,0,0};
            #pragma unroll
            for (int ks = 0; ks < 4; ++ks) {
                #pragma unroll
                for (int t = 0; t < 2; ++t)
                    acc[t] = __builtin_amdgcn_mfma_f32_16x16x32_bf16(wfr[ks], xf[t][ks], acc[t], 0,0,0);
            }
            float4 bias = *(const float4*)(cb + mat * 128 + c * 16 + kg * 4);
            #pragma unroll
            for (int t = 0; t < 2; ++t) {
                int xrow = r0 + t * 16 + lrow;
                if (xrow < nrows) {
                    ushort4 o;
                    o.x = f2bf(acc[t][0] + bias.x); o.y = f2bf(acc[t][1] + bias.y);
                    o.z = f2bf(acc[t][2] + bias.z); o.w = f2bf(acc[t][3] + bias.w);
                    *(ushort4*)(gm + (size_t)xrow * 128 + c * 16 + kg * 4) = o;
                }
            }
        }
    }
}

// ---- kernel C (R3 form): one wave per node; wave-uniform deg -> loads for
//      k >= deg are fully skipped by scalar branches. Split load/consume. ----
__global__ __launch_bounds__(256) void gather_out(
    const int* __restrict__ ci, const unsigned short* __restrict__ g,
    const float* __restrict__ bfv, float* __restrict__ out,
    float* __restrict__ maskout, int nnodes)
{
    int n    = (int)((blockIdx.x * blockDim.x + threadIdx.x) >> 6);
    int lane = threadIdx.x & 63;
    if (n >= nnodes) return;

    int civ = ci[n * 8 + (lane & 7)];
    unsigned long long bal = __ballot(civ == -1);
    int cnt = __popcll(bal & 0xFFull);
    int deg = (cnt == 8) ? 0 : (7 - cnt);     // wave-uniform

    int d = lane * 2;
    float2 bfd = *(const float2*)(bfv + d);
    const unsigned short* g1 = g;
    const unsigned short* g2 = g + (size_t)nnodes * 128;

    // load phase: all needed rows in flight before any consumption.
    unsigned ua[7], ub[7];
    #pragma unroll
    for (int k = 0; k < 7; ++k) {
        int i = __shfl(civ, k);
        ua[k] = (k < deg) ? *(const unsigned*)(g1 + (size_t)i * 128 + d) : 0u;
    }
    bool two = (deg >= 2);
    #pragma unroll
    for (int k = 1; k < 8; ++k) {
        int i = __shfl(civ, k);
        ub[k - 1] = (two && k <= deg) ? *(const unsigned*)(g2 + (size_t)i * 128 + d) : 0u;
    }

    // consume + store phase (branch-free adds; zero bits are exact no-ops)
    size_t outbase = (size_t)n * 7 * 128;
    #pragma unroll
    for (int j = 0; j < 7; ++j) {
        float s0 = bfd.x + bf2f((unsigned short)(ua[j] & 0xFFFFu))
                         + bf2f((unsigned short)(ub[j] & 0xFFFFu));
        float s1 = bfd.y + bf2f((unsigned short)(ua[j] >> 16))
                         + bf2f((unsigned short)(ub[j] >> 16));
        f32x2 o; o[0] = s0; o[1] = s1;
        __builtin_nontemporal_store(o, (f32x2*)(out + outbase + (size_t)j * 128 + d));
    }
    if (lane < 7)
        __builtin_nontemporal_store((lane < deg) ? 1.0f : 0.0f, maskout + n * 7 + lane);
}

extern "C" void kernel_launch(void* const* d_in, const int* in_sizes, int n_in,
                              void* d_out, int out_size, void* d_ws, size_t ws_size,
                              hipStream_t stream) {
    const float* x   = (const float*)d_in[0];
    const float* w1  = (const float*)d_in[1];
    const float* b1  = (const float*)d_in[2];
    const float* w2  = (const float*)d_in[3];
    const float* b2  = (const float*)d_in[4];
    const float* wf  = (const float*)d_in[5];
    const float* bfv = (const float*)d_in[6];
    const int*   ci  = (const int*)d_in[7];

    int nrows = in_sizes[0] / 128;

    size_t gbytes = (size_t)2 * nrows * 128 * 2;
    unsigned short* g   = (unsigned short*)d_ws;
    unsigned short* wcT = (unsigned short*)((char*)d_ws + ((gbytes + 255) & ~(size_t)255));
    float*          cb  = (float*)((char*)wcT + 2 * 128 * 128 * 2);

    fuse_weights<<<2 * 129, 128, 0, stream>>>(w1, b1, w2, b2, wf, wcT, cb);

    int nblk = (nrows + 4 * WAVE_ROWS - 1) / (4 * WAVE_ROWS);
    gemm_g<<<nblk, 256, 0, stream>>>(x, wcT, cb, g, nrows);

    int rows = nrows * 7;
    int cblk = (nrows * 64 + 255) / 256;
    float* out = (float*)d_out;
    gather_out<<<cblk, 256, 0, stream>>>(ci, g, bfv, out, out + (size_t)rows * 128, nrows);
}

// Round 10
// 123.122 us; speedup vs baseline: 1.0627x; 1.0627x over previous
//
#include <hip/hip_runtime.h>
#include <stdint.h>

typedef short bf16x8 __attribute__((ext_vector_type(8)));
typedef float f32x4  __attribute__((ext_vector_type(4)));
typedef float f32x2  __attribute__((ext_vector_type(2)));

__device__ __forceinline__ unsigned short f2bf(float f) {
    unsigned int u = __float_as_uint(f);
    u += 0x7FFFu + ((u >> 16) & 1u);
    return (unsigned short)(u >> 16);
}
__device__ __forceinline__ float bf2f(unsigned short h) {
    return __uint_as_float(((unsigned int)h) << 16);
}

// ---- kernel A: fold W1f = w1@wf, W2f = w2@wf (store transposed bf16), cb = b@wf ----
__global__ void fuse_weights(const float* __restrict__ w1, const float* __restrict__ b1,
                             const float* __restrict__ w2, const float* __restrict__ b2,
                             const float* __restrict__ wf,
                             unsigned short* __restrict__ wcT,  // [2][128 cols][128 k]
                             float* __restrict__ cb)            // [2][128]
{
    int mat = blockIdx.x / 129;
    int kk  = blockIdx.x % 129;
    int c   = threadIdx.x;
    const float* w = (mat == 0) ? w1 : w2;
    const float* b = (mat == 0) ? b1 : b2;
    float acc = 0.f;
    if (kk < 128) {
        #pragma unroll 8
        for (int j = 0; j < 128; ++j) acc += w[kk * 128 + j] * wf[j * 128 + c];
        wcT[mat * 16384 + c * 128 + kk] = f2bf(acc);
    } else {
        #pragma unroll 8
        for (int j = 0; j < 128; ++j) acc += b[j] * wf[j * 128 + c];
        cb[mat * 128 + c] = acc;
    }
}

// ---- kernel B (R3 form): g[mat] = x @ Wc[mat] + cb[mat] -> bf16 [2][nrows][128] ----
#define WAVE_ROWS 64
__global__ __launch_bounds__(256) void gemm_g(
    const float* __restrict__ x, const unsigned short* __restrict__ wcT,
    const float* __restrict__ cb, unsigned short* __restrict__ g, int nrows)
{
    int lane = threadIdx.x & 63;
    int wid  = threadIdx.x >> 6;
    int r0   = (blockIdx.x * 4 + wid) * WAVE_ROWS;
    if (r0 >= nrows) return;
    int lrow = lane & 15;
    int kg   = lane >> 4;

    bf16x8 xf[4][4];   // [rowtile][kstep]
    #pragma unroll
    for (int t = 0; t < 4; ++t) {
        int row = r0 + t * 16 + lrow;
        bool v  = row < nrows;
        #pragma unroll
        for (int ks = 0; ks < 4; ++ks) {
            int k0 = ks * 32 + kg * 8;
            float4 p0 = v ? *(const float4*)(x + (size_t)row * 128 + k0)     : float4{0,0,0,0};
            float4 p1 = v ? *(const float4*)(x + (size_t)row * 128 + k0 + 4) : float4{0,0,0,0};
            bf16x8 f;
            f[0] = (short)f2bf(p0.x); f[1] = (short)f2bf(p0.y);
            f[2] = (short)f2bf(p0.z); f[3] = (short)f2bf(p0.w);
            f[4] = (short)f2bf(p1.x); f[5] = (short)f2bf(p1.y);
            f[6] = (short)f2bf(p1.z); f[7] = (short)f2bf(p1.w);
            xf[t][ks] = f;
        }
    }

    #pragma unroll
    for (int mat = 0; mat < 2; ++mat) {
        unsigned short* gm = g + (size_t)mat * nrows * 128;
        const unsigned short* wT = wcT + mat * 16384;
        #pragma unroll 2
        for (int c = 0; c < 8; ++c) {
            bf16x8 wfr[4];
            const unsigned short* wb = wT + (size_t)(c * 16 + lrow) * 128 + kg * 8;
            #pragma unroll
            for (int ks = 0; ks < 4; ++ks)
                wfr[ks] = *(const bf16x8*)(wb + ks * 32);
            f32x4 acc[4];
            #pragma unroll
            for (int t = 0; t < 4; ++t) acc[t] = f32x4{0,0,0,0};
            #pragma unroll
            for (int ks = 0; ks < 4; ++ks) {
                #pragma unroll
                for (int t = 0; t < 4; ++t)
                    acc[t] = __builtin_amdgcn_mfma_f32_16x16x32_bf16(wfr[ks], xf[t][ks], acc[t], 0,0,0);
            }
            float4 bias = *(const float4*)(cb + mat * 128 + c * 16 + kg * 4);
            #pragma unroll
            for (int t = 0; t < 4; ++t) {
                int xrow = r0 + t * 16 + lrow;
                if (xrow < nrows) {
                    ushort4 o;
                    o.x = f2bf(acc[t][0] + bias.x); o.y = f2bf(acc[t][1] + bias.y);
                    o.z = f2bf(acc[t][2] + bias.z); o.w = f2bf(acc[t][3] + bias.w);
                    *(ushort4*)(gm + (size_t)xrow * 128 + c * 16 + kg * 4) = o;
                }
            }
        }
    }
}

// ---- kernel C: 2 nodes SEQUENTIALLY per wave; both degs wave-uniform.
//      All loads (up to 14 rows) issued before any consumption. ----
__global__ __launch_bounds__(256) void gather_out(
    const int* __restrict__ ci, const unsigned short* __restrict__ g,
    const float* __restrict__ bfv, float* __restrict__ out,
    float* __restrict__ maskout, int nnodes)
{
    int wv   = (int)((blockIdx.x * blockDim.x + threadIdx.x) >> 6);
    int lane = threadIdx.x & 63;
    int n0   = wv * 2;
    if (n0 >= nnodes) return;
    int n1   = n0 + 1;
    bool h1  = n1 < nnodes;

    // lanes 0..7: node0's ci, lanes 8..15: node1's ci (replicated across wave)
    int cidx = n0 * 8 + (lane & 15);
    if (!h1 && (lane & 15) >= 8) cidx = n0 * 8 + (lane & 7);
    int civ = ci[cidx];
    unsigned long long bal = __ballot(civ == -1);
    int cnt0 = __popcll(bal & 0xFFull);
    int cnt1 = __popcll((bal >> 8) & 0xFFull);
    int deg0 = (cnt0 == 8) ? 0 : (7 - cnt0);   // wave-uniform
    int deg1 = (cnt1 == 8) ? 0 : (7 - cnt1);   // wave-uniform
    if (!h1) deg1 = 0;

    int d = lane * 2;
    float2 bfd = *(const float2*)(bfv + d);
    const unsigned short* g1 = g;
    const unsigned short* g2 = g + (size_t)nnodes * 128;

    // ---- load phase: everything in flight before first use ----
    unsigned ua0[7], ub0[7], ua1[7], ub1[7];
    #pragma unroll
    for (int k = 0; k < 7; ++k) {
        int i = __shfl(civ, k);
        ua0[k] = (k < deg0) ? *(const unsigned*)(g1 + (size_t)i * 128 + d) : 0u;
    }
    #pragma unroll
    for (int k = 0; k < 7; ++k) {
        int i = __shfl(civ, 8 + k);
        ua1[k] = (k < deg1) ? *(const unsigned*)(g1 + (size_t)i * 128 + d) : 0u;
    }
    bool two0 = (deg0 >= 2), two1 = (deg1 >= 2);
    #pragma unroll
    for (int k = 1; k < 8; ++k) {
        int i = __shfl(civ, k);
        ub0[k - 1] = (two0 && k <= deg0) ? *(const unsigned*)(g2 + (size_t)i * 128 + d) : 0u;
    }
    #pragma unroll
    for (int k = 1; k < 8; ++k) {
        int i = __shfl(civ, 8 + k);
        ub1[k - 1] = (two1 && k <= deg1) ? *(const unsigned*)(g2 + (size_t)i * 128 + d) : 0u;
    }

    // ---- consume + store (branch-free adds; zero bits are exact no-ops) ----
    size_t ob0 = (size_t)n0 * 7 * 128;
    #pragma unroll
    for (int j = 0; j < 7; ++j) {
        float s0 = bfd.x + bf2f((unsigned short)(ua0[j] & 0xFFFFu))
                         + bf2f((unsigned short)(ub0[j] & 0xFFFFu));
        float s1 = bfd.y + bf2f((unsigned short)(ua0[j] >> 16))
                         + bf2f((unsigned short)(ub0[j] >> 16));
        f32x2 o; o[0] = s0; o[1] = s1;
        __builtin_nontemporal_store(o, (f32x2*)(out + ob0 + (size_t)j * 128 + d));
    }
    if (h1) {
        size_t ob1 = (size_t)n1 * 7 * 128;
        #pragma unroll
        for (int j = 0; j < 7; ++j) {
            float s0 = bfd.x + bf2f((unsigned short)(ua1[j] & 0xFFFFu))
                             + bf2f((unsigned short)(ub1[j] & 0xFFFFu));
            float s1 = bfd.y + bf2f((unsigned short)(ua1[j] >> 16))
                             + bf2f((unsigned short)(ub1[j] >> 16));
            f32x2 o; o[0] = s0; o[1] = s1;
            __builtin_nontemporal_store(o, (f32x2*)(out + ob1 + (size_t)j * 128 + d));
        }
    }
    if (lane < 7)
        __builtin_nontemporal_store((lane < deg0) ? 1.0f : 0.0f, maskout + n0 * 7 + lane);
    else if (h1 && lane >= 8 && lane < 15)
        __builtin_nontemporal_store(((lane - 8) < deg1) ? 1.0f : 0.0f, maskout + n1 * 7 + (lane - 8));
}

extern "C" void kernel_launch(void* const* d_in, const int* in_sizes, int n_in,
                              void* d_out, int out_size, void* d_ws, size_t ws_size,
                              hipStream_t stream) {
    const float* x   = (const float*)d_in[0];
    const float* w1  = (const float*)d_in[1];
    const float* b1  = (const float*)d_in[2];
    const float* w2  = (const float*)d_in[3];
    const float* b2  = (const float*)d_in[4];
    const float* wf  = (const float*)d_in[5];
    const float* bfv = (const float*)d_in[6];
    const int*   ci  = (const int*)d_in[7];

    int nrows = in_sizes[0] / 128;

    size_t gbytes = (size_t)2 * nrows * 128 * 2;
    unsigned short* g   = (unsigned short*)d_ws;
    unsigned short* wcT = (unsigned short*)((char*)d_ws + ((gbytes + 255) & ~(size_t)255));
    float*          cb  = (float*)((char*)wcT + 2 * 128 * 128 * 2);

    fuse_weights<<<2 * 129, 128, 0, stream>>>(w1, b1, w2, b2, wf, wcT, cb);

    int nblk = (nrows + 4 * WAVE_ROWS - 1) / (4 * WAVE_ROWS);
    gemm_g<<<nblk, 256, 0, stream>>>(x, wcT, cb, g, nrows);

    int rows = nrows * 7;
    int npairs = (nrows + 1) / 2;
    int cblk = (npairs * 64 + 255) / 256;
    float* out = (float*)d_out;
    gather_out<<<cblk, 256, 0, stream>>>(ci, g, bfv, out, out + (size_t)rows * 128, nrows);
}